// Round 3
// baseline (1077.360 us; speedup 1.0000x reference)
//
#include <hip/hip_runtime.h>
#include <hip/hip_bf16.h>
#include <cstdint>
#include <cstddef>

#define BATCH 64
#define SEQ   2048
#define ENCD  1024
#define DECD  1024
#define ATT   512

typedef short short8 __attribute__((ext_vector_type(8)));
typedef float f32x4  __attribute__((ext_vector_type(4)));

__device__ __forceinline__ uint32_t bf16r(float x) {
  uint32_t u = __float_as_uint(x);
  return (u + 0x7fffu + ((u >> 16) & 1u)) >> 16;  // RNE
}
__device__ __forceinline__ uint32_t pack_bf16(float lo, float hi) {
  return bf16r(lo) | (bf16r(hi) << 16);
}
__device__ __forceinline__ float fast_tanh(float x) {
  float t = __expf(2.0f * fabsf(x));      // e^{2|x|} >= 1; inf-safe
  float r = 1.0f - 2.0f / (t + 1.0f);
  return copysignf(r, x);
}

// ---- W_enc fp32 -> bf16, tiled [ntile][kstep] 16KB blocks, XOR-swizzled ----
__global__ void convert_W_kernel(const float* __restrict__ W, char* __restrict__ wsW) {
  int tid = blockIdx.x * 256 + threadIdx.x;      // 65536 threads, 8 elems each
  int a  = tid >> 7;
  int e0 = (tid & 127) << 3;
  const float4* src = reinterpret_cast<const float4*>(W + (size_t)a * ENCD + e0);
  float4 f0 = src[0], f1 = src[1];
  uint4 u;
  u.x = pack_bf16(f0.x, f0.y);
  u.y = pack_bf16(f0.z, f0.w);
  u.z = pack_bf16(f1.x, f1.y);
  u.w = pack_bf16(f1.z, f1.w);
  int ntile = a >> 7, row = a & 127;
  int kstep = e0 >> 6, colb = (e0 & 63) << 1;
  size_t off = (size_t)(ntile * 16 + kstep) * 16384
             + (size_t)row * 128 + (colb ^ ((row & 7) << 4));
  *reinterpret_cast<uint4*>(wsW + off) = u;
}

// ---- proj_dec[b][a] = dot(dec[b,:], W_dec[a,:]) ----
__global__ void proj_dec_kernel(const float* __restrict__ dec,
                                const float* __restrict__ Wd,
                                float* __restrict__ pd) {
  __shared__ float drow[DECD];
  int b = blockIdx.x, t = threadIdx.x;           // 512 threads
  drow[t]       = dec[(size_t)b * DECD + t];
  drow[t + 512] = dec[(size_t)b * DECD + t + 512];
  __syncthreads();
  const float4* w4 = reinterpret_cast<const float4*>(Wd + (size_t)t * DECD);
  const float4* d4 = reinterpret_cast<const float4*>(drow);
  float acc = 0.f;
  #pragma unroll 8
  for (int i = 0; i < DECD / 4; ++i) {
    float4 wv = w4[i], dv = d4[i];
    acc += wv.x * dv.x + wv.y * dv.y + wv.z * dv.z + wv.w * dv.w;
  }
  pd[(size_t)b * ATT + t] = acc;
}

// ---- fused bf16-MFMA score GEMM: scores[b,s] += sum_a tanh(enc@W^T + pd)*v ----
__global__ __launch_bounds__(256) void score_gemm_kernel(
    const float* __restrict__ enc, const char* __restrict__ wsW,
    const float* __restrict__ pd, const float* __restrict__ v,
    float* __restrict__ scores)
{
  __shared__ __align__(16) char lds[32768];
  char* ldsA = lds;            // 128 x 64 bf16, swizzled
  char* ldsB = lds + 16384;    // 128 x 64 bf16, swizzled

  // XCD-bijective swizzle: 4096 blocks, 8 XCDs, 512 works per XCD chunk.
  // ntile fastest => the 4 blocks sharing an enc tile are neighbors on one XCD.
  int lid   = blockIdx.x;
  int work  = ((lid & 7) << 9) | (lid >> 3);
  int ntile = work & 3;
  int stile = (work >> 2) & 15;
  int b     = work >> 6;

  int tid  = threadIdx.x;
  int lane = tid & 63;
  int wave = tid >> 6;
  int wrow = wave >> 1, wcol = wave & 1;

  const float* encT = enc + ((size_t)b * SEQ + stile * 128) * ENCD;
  const char*  wsB  = wsW + (size_t)ntile * 16 * 16384;

  f32x4 acc[4][4];
  #pragma unroll
  for (int mi = 0; mi < 4; ++mi)
    #pragma unroll
    for (int ni = 0; ni < 4; ++ni)
      acc[mi][ni] = (f32x4){0.f, 0.f, 0.f, 0.f};

  int arow_st = tid >> 4;         // 0..15
  int acolf   = (tid & 15) << 2;  // 0..60

  for (int ks = 0; ks < ENCD / 64; ++ks) {
    __syncthreads();  // prev compute done before overwrite
    // B tile: async global->LDS, identity copy of pre-swizzled 16 KB block
    {
      const char* src = wsB + (size_t)ks * 16384 + wave * 1024 + lane * 16;
      char*       dst = ldsB + wave * 1024;
      #pragma unroll
      for (int c = 0; c < 4; ++c) {
        __builtin_amdgcn_global_load_lds(
            (const __attribute__((address_space(1))) uint32_t*)(src + c * 4096),
            (__attribute__((address_space(3))) uint32_t*)(dst + c * 4096),
            16, 0, 0);
      }
    }
    // A tile: fp32 load -> bf16 convert -> swizzled ds_write_b64
    {
      const float* srcA = encT + ks * 64;
      #pragma unroll
      for (int rnd = 0; rnd < 8; ++rnd) {
        int row = rnd * 16 + arow_st;
        float4 fv = *reinterpret_cast<const float4*>(srcA + (size_t)row * ENCD + acolf);
        uint2 p;
        p.x = pack_bf16(fv.x, fv.y);
        p.y = pack_bf16(fv.z, fv.w);
        int colb = acolf << 1;
        *reinterpret_cast<uint2*>(ldsA + (size_t)row * 128 + (colb ^ ((row & 7) << 4))) = p;
      }
    }
    __syncthreads();
    #pragma unroll
    for (int kk = 0; kk < 2; ++kk) {
      int kb = (kk * 32 + ((lane >> 4) << 3)) << 1;
      short8 af[4], bfr[4];
      #pragma unroll
      for (int mi = 0; mi < 4; ++mi) {
        int row = wrow * 64 + mi * 16 + (lane & 15);
        af[mi] = *reinterpret_cast<const short8*>(ldsA + row * 128 + (kb ^ ((row & 7) << 4)));
      }
      #pragma unroll
      for (int ni = 0; ni < 4; ++ni) {
        int row = wcol * 64 + ni * 16 + (lane & 15);
        bfr[ni] = *reinterpret_cast<const short8*>(ldsB + row * 128 + (kb ^ ((row & 7) << 4)));
      }
      #pragma unroll
      for (int mi = 0; mi < 4; ++mi)
        #pragma unroll
        for (int ni = 0; ni < 4; ++ni)
          acc[mi][ni] = __builtin_amdgcn_mfma_f32_16x16x32_bf16(
              af[mi], bfr[ni], acc[mi][ni], 0, 0, 0);
    }
  }

  // Epilogue: score partial = sum over this block's 128 a-cols of tanh(.+pd)*v
  int a0 = ntile * 128 + wcol * 64 + (lane & 15);
  float vv[4], pdv[4];
  #pragma unroll
  for (int ni = 0; ni < 4; ++ni) {
    int acol = a0 + ni * 16;
    vv[ni]  = v[acol];
    pdv[ni] = pd[(size_t)b * ATT + acol];
  }
  float* srow_base = scores + (size_t)b * SEQ + stile * 128 + wrow * 64 + ((lane >> 4) << 2);
  #pragma unroll
  for (int mi = 0; mi < 4; ++mi) {
    #pragma unroll
    for (int j = 0; j < 4; ++j) {
      float val = 0.f;
      #pragma unroll
      for (int ni = 0; ni < 4; ++ni)
        val += fast_tanh(acc[mi][ni][j] + pdv[ni]) * vv[ni];
      val += __shfl_xor(val, 1);
      val += __shfl_xor(val, 2);
      val += __shfl_xor(val, 4);
      val += __shfl_xor(val, 8);
      if ((lane & 15) == 0)
        atomicAdd(srow_base + mi * 16 + j, val);
    }
  }
}

// ---- masked softmax over S, in-place in d_out's attn region ----
__global__ void softmax_kernel(const int* __restrict__ mask, float* __restrict__ attn) {
  int b = blockIdx.x, t = threadIdx.x;           // 256 threads
  int lane = t & 63, wave = t >> 6;
  __shared__ float wredm[4], wreds[4];
  float vals[8];
  float lmax = -3.0e38f;
  #pragma unroll
  for (int i = 0; i < 8; ++i) {
    int s = t + i * 256;
    float sc = attn[(size_t)b * SEQ + s];
    sc = (mask[(size_t)b * SEQ + s] == 0) ? -3.0e38f : sc;
    vals[i] = sc;
    lmax = fmaxf(lmax, sc);
  }
  #pragma unroll
  for (int m = 1; m <= 32; m <<= 1) lmax = fmaxf(lmax, __shfl_xor(lmax, m));
  if (lane == 0) wredm[wave] = lmax;
  __syncthreads();
  float bmax = fmaxf(fmaxf(wredm[0], wredm[1]), fmaxf(wredm[2], wredm[3]));
  float lsum = 0.f;
  #pragma unroll
  for (int i = 0; i < 8; ++i) {
    float e = (vals[i] <= -1.0e37f) ? 0.f : __expf(vals[i] - bmax);
    vals[i] = e;
    lsum += e;
  }
  #pragma unroll
  for (int m = 1; m <= 32; m <<= 1) lsum += __shfl_xor(lsum, m);
  if (lane == 0) wreds[wave] = lsum;
  __syncthreads();
  float inv = 1.0f / fmaxf(wreds[0] + wreds[1] + wreds[2] + wreds[3], 1e-37f);
  #pragma unroll
  for (int i = 0; i < 8; ++i)
    attn[(size_t)b * SEQ + t + i * 256] = vals[i] * inv;
}

// ---- context[b,e] = sum_s attn[b,s] * enc[b,s,e] (fp32 streaming) ----
__global__ void context_kernel(const float* __restrict__ enc,
                               const float* __restrict__ attn,
                               float* __restrict__ ctx) {
  __shared__ float arow[SEQ];
  __shared__ __align__(16) float partial[8][128];
  int b = blockIdx.x >> 3, ec = blockIdx.x & 7;  // 512 blocks
  int t = threadIdx.x;                           // 256 threads
  #pragma unroll
  for (int i = 0; i < 8; ++i)
    arow[t + i * 256] = attn[(size_t)b * SEQ + t + i * 256];
  __syncthreads();
  int g = t >> 5, lq = t & 31;
  const float* ebase = enc + (size_t)b * SEQ * ENCD + ec * 128 + lq * 4;
  float4 acc = {0.f, 0.f, 0.f, 0.f};
  for (int s = g; s < SEQ; s += 8) {
    float a = arow[s];
    float4 ev = *reinterpret_cast<const float4*>(ebase + (size_t)s * ENCD);
    acc.x += a * ev.x; acc.y += a * ev.y; acc.z += a * ev.z; acc.w += a * ev.w;
  }
  *reinterpret_cast<float4*>(&partial[g][lq * 4]) = acc;
  __syncthreads();
  if (t < 128) {
    float r = 0.f;
    #pragma unroll
    for (int gg = 0; gg < 8; ++gg) r += partial[gg][t];
    ctx[(size_t)b * ENCD + ec * 128 + t] = r;
  }
}

extern "C" void kernel_launch(void* const* d_in, const int* in_sizes, int n_in,
                              void* d_out, int out_size, void* d_ws, size_t ws_size,
                              hipStream_t stream) {
  const float* dec  = (const float*)d_in[0];
  const float* enc  = (const float*)d_in[1];
  const int*   mask = (const int*)d_in[2];
  const float* Wenc = (const float*)d_in[3];
  const float* Wdec = (const float*)d_in[4];
  const float* v    = (const float*)d_in[5];

  float* out  = (float*)d_out;
  float* ctx  = out;                 // (64,1024)
  float* attn = out + BATCH * ENCD;  // (64,2048): scores then attn in-place

  char*  ws  = (char*)d_ws;
  char*  wsW = ws;                        // 1 MiB: W_enc bf16 tiled+swizzled
  float* pd  = (float*)(ws + (1 << 20)); // 128 KiB: proj_dec

  hipMemsetAsync(attn, 0, (size_t)BATCH * SEQ * sizeof(float), stream);
  convert_W_kernel<<<256, 256, 0, stream>>>(Wenc, wsW);
  proj_dec_kernel<<<64, 512, 0, stream>>>(dec, Wdec, pd);
  score_gemm_kernel<<<4096, 256, 0, stream>>>(enc, wsW, pd, v, attn);
  softmax_kernel<<<64, 256, 0, stream>>>(mask, attn);
  context_kernel<<<512, 256, 0, stream>>>(enc, attn, ctx);
}